// Round 1
// baseline (18395.396 us; speedup 1.0000x reference)
//
#include <hip/hip_runtime.h>
#include <cstddef>

#define BB 64      // batch
#define TT 512     // time steps
#define NN 250     // useful input features (alpha=1.0 block is zero)
#define HH 512     // hidden
#define NB (NN*BB) // 16000 floats per timestep slice
#define HB (HH*BB) // 32768 floats per hidden state

__device__ __forceinline__ float sigmoidf_(float x) { return 1.0f / (1.0f + expf(-x)); }

// ---------------- transpose x[b][t][n] -> xT[t][n][b] ----------------
__global__ __launch_bounds__(256) void k_transpose(const float* __restrict__ x,
                                                   float* __restrict__ xT) {
    const int t = blockIdx.x;
    const int n = blockIdx.y * 4 + (threadIdx.x >> 6);
    const int b = threadIdx.x & 63;
    if (n < NN)
        xT[(size_t)t * NB + n * BB + b] = x[(size_t)b * (TT * NN) + t * NN + n];
}

// ---------------- w[d] = (d+1e-6)^-0.5, rowsum[t] = sum_{d=1..t} w[d] ----------------
__global__ __launch_bounds__(512) void k_wrow(float* __restrict__ w, float* __restrict__ rowsum) {
    __shared__ float sw[TT];
    const int d = threadIdx.x;
    const float wd = (d >= 1) ? (1.0f / sqrtf((float)d + 1e-6f)) : 0.0f;
    sw[d] = wd;
    w[d] = wd;
    __syncthreads();
    float s = 0.0f;
    for (int j = 1; j <= d; ++j) s += sw[j];
    rowsum[d] = s;
}

// ---------------- caputo: featsT[t][n][b] = coef*(x*rowsum[t] - sum_{j<t} w[t-j]*x[j]) ----
__global__ __launch_bounds__(256) void k_caputo(const float* __restrict__ xT,
                                                const float* __restrict__ w,
                                                const float* __restrict__ rowsum,
                                                float* __restrict__ featsT) {
    const float COEF = 0.5641895835477563f;  // 1/gamma(0.5)
    const int t0 = blockIdx.x * 4;
    const int nb0 = blockIdx.y * 1024 + threadIdx.x;
    float acc[4][4];
#pragma unroll
    for (int a = 0; a < 4; ++a)
#pragma unroll
        for (int e = 0; e < 4; ++e) acc[a][e] = 0.0f;

    for (int j = 0; j < t0; ++j) {
        const float* xj = xT + (size_t)j * NB;
        const float wt0 = w[t0 - j];
        const float wt1 = w[t0 + 1 - j];
        const float wt2 = w[t0 + 2 - j];
        const float wt3 = w[t0 + 3 - j];
#pragma unroll
        for (int e = 0; e < 4; ++e) {
            const int nb = nb0 + e * 256;
            const float xv = (nb < NB) ? xj[nb] : 0.0f;
            acc[0][e] = fmaf(wt0, xv, acc[0][e]);
            acc[1][e] = fmaf(wt1, xv, acc[1][e]);
            acc[2][e] = fmaf(wt2, xv, acc[2][e]);
            acc[3][e] = fmaf(wt3, xv, acc[3][e]);
        }
    }
    // tail j = t0 .. t0+2 : only rows with t > j
#pragma unroll
    for (int dj = 0; dj < 3; ++dj) {
        const int j = t0 + dj;
        const float* xj = xT + (size_t)j * NB;
#pragma unroll
        for (int e = 0; e < 4; ++e) {
            const int nb = nb0 + e * 256;
            const float xv = (nb < NB) ? xj[nb] : 0.0f;
#pragma unroll
            for (int tt = 0; tt < 4; ++tt)
                if (tt > dj) acc[tt][e] = fmaf(w[tt - dj], xv, acc[tt][e]);
        }
    }
#pragma unroll
    for (int tt = 0; tt < 4; ++tt) {
        const int t = t0 + tt;
        const float rs = rowsum[t];
        const float* xt = xT + (size_t)t * NB;
        float* ft = featsT + (size_t)t * NB;
#pragma unroll
        for (int e = 0; e < 4; ++e) {
            const int nb = nb0 + e * 256;
            if (nb < NB) ft[nb] = COEF * fmaf(xt[nb], rs, -acc[tt][e]);
        }
    }
}

// ---------------- 4-row dot helper: acc[q] += sum_k Wq[k]*v[k*BB] ----------------
__device__ __forceinline__ void dot4(const float* __restrict__ w0, const float* __restrict__ w1,
                                     const float* __restrict__ w2, const float* __restrict__ w3,
                                     const float* __restrict__ v, int len, float acc[4]) {
    const int l4 = len >> 2;
    for (int i = 0; i < l4; ++i) {
        const float4 a0 = *reinterpret_cast<const float4*>(w0 + 4 * i);
        const float4 a1 = *reinterpret_cast<const float4*>(w1 + 4 * i);
        const float4 a2 = *reinterpret_cast<const float4*>(w2 + 4 * i);
        const float4 a3 = *reinterpret_cast<const float4*>(w3 + 4 * i);
        const float v0 = v[(4 * i + 0) * BB];
        const float v1 = v[(4 * i + 1) * BB];
        const float v2 = v[(4 * i + 2) * BB];
        const float v3 = v[(4 * i + 3) * BB];
        acc[0] = fmaf(a0.x, v0, fmaf(a0.y, v1, fmaf(a0.z, v2, fmaf(a0.w, v3, acc[0]))));
        acc[1] = fmaf(a1.x, v0, fmaf(a1.y, v1, fmaf(a1.z, v2, fmaf(a1.w, v3, acc[1]))));
        acc[2] = fmaf(a2.x, v0, fmaf(a2.y, v1, fmaf(a2.z, v2, fmaf(a2.w, v3, acc[2]))));
        acc[3] = fmaf(a3.x, v0, fmaf(a3.y, v1, fmaf(a3.z, v2, fmaf(a3.w, v3, acc[3]))));
    }
    for (int k = l4 * 4; k < len; ++k) {
        const float vv = v[k * BB];
        acc[0] = fmaf(w0[k], vv, acc[0]);
        acc[1] = fmaf(w1[k], vv, acc[1]);
        acc[2] = fmaf(w2[k], vv, acc[2]);
        acc[3] = fmaf(w3[k], vv, acc[3]);
    }
}

// ---------------- one wavefront step: layer0 @ t=s (s<512), layer1 @ t=s-1 (s>=1) --------
// state layout: hT[buf][k][b] (k-major, b minor -> coalesced along lanes)
__global__ __launch_bounds__(1024) void k_step(
    const float* __restrict__ featsT,
    const float* __restrict__ Wih0, const float* __restrict__ Whh0,
    const float* __restrict__ bih0, const float* __restrict__ bhh0,
    const float* __restrict__ Wih1, const float* __restrict__ Whh1,
    const float* __restrict__ bih1, const float* __restrict__ bhh1,
    float* __restrict__ h0T, float* __restrict__ c0T,
    float* __restrict__ h1T, float* __restrict__ c1T, int s) {
    __shared__ float part[16][4][64];
    const int tid = threadIdx.x;
    const int b = tid & 63;
    const int r = tid >> 6;   // wave 0..15
    const int unit = r & 3;   // 0,1 -> layer0 local unit; 2,3 -> layer1 local unit
    const int kq = r >> 2;    // k-quarter 0..3
    const int rd = (s + 1) & 1;
    const int wr = s & 1;
    const float* __restrict__ h0p = h0T + (size_t)rd * HB;
    float acc[4] = {0.f, 0.f, 0.f, 0.f};

    if (unit < 2) {
        if (s < TT) {
            const int hu = blockIdx.x * 2 + unit;
            {   // input (caputo feats) segment, n in [kq*64, ...)
                const int n0 = kq * 64;
                const int n1 = (kq == 3) ? NN : (n0 + 64);
                dot4(Wih0 + (size_t)(0 * HH + hu) * 500 + n0,
                     Wih0 + (size_t)(1 * HH + hu) * 500 + n0,
                     Wih0 + (size_t)(2 * HH + hu) * 500 + n0,
                     Wih0 + (size_t)(3 * HH + hu) * 500 + n0,
                     featsT + (size_t)s * NB + n0 * BB + b, n1 - n0, acc);
            }
            {   // recurrent segment
                const int k0 = kq * 128;
                dot4(Whh0 + (size_t)(0 * HH + hu) * HH + k0,
                     Whh0 + (size_t)(1 * HH + hu) * HH + k0,
                     Whh0 + (size_t)(2 * HH + hu) * HH + k0,
                     Whh0 + (size_t)(3 * HH + hu) * HH + k0,
                     h0p + k0 * BB + b, 128, acc);
            }
        }
    } else {
        if (s >= 1) {
            const int hu = blockIdx.x * 2 + (unit - 2);
            const float* __restrict__ h1p = h1T + (size_t)rd * HB;
            const int k0 = kq * 128;
            dot4(Wih1 + (size_t)(0 * HH + hu) * HH + k0,
                 Wih1 + (size_t)(1 * HH + hu) * HH + k0,
                 Wih1 + (size_t)(2 * HH + hu) * HH + k0,
                 Wih1 + (size_t)(3 * HH + hu) * HH + k0,
                 h0p + k0 * BB + b, 128, acc);
            dot4(Whh1 + (size_t)(0 * HH + hu) * HH + k0,
                 Whh1 + (size_t)(1 * HH + hu) * HH + k0,
                 Whh1 + (size_t)(2 * HH + hu) * HH + k0,
                 Whh1 + (size_t)(3 * HH + hu) * HH + k0,
                 h1p + k0 * BB + b, 128, acc);
        }
    }
    part[r][0][b] = acc[0];
    part[r][1][b] = acc[1];
    part[r][2][b] = acc[2];
    part[r][3][b] = acc[3];
    __syncthreads();
    if (kq == 0) {
        const bool isL1 = (unit >= 2);
        const bool active = isL1 ? (s >= 1) : (s < TT);
        if (active) {
            const int hu = blockIdx.x * 2 + (unit & 1);
            const float* bi = isL1 ? bih1 : bih0;
            const float* bh = isL1 ? bhh1 : bhh0;
            float g4[4];
#pragma unroll
            for (int q = 0; q < 4; ++q)
                g4[q] = part[unit][q][b] + part[unit + 4][q][b] + part[unit + 8][q][b] +
                        part[unit + 12][q][b] + bi[q * HH + hu] + bh[q * HH + hu];
            const float gi = sigmoidf_(g4[0]);
            const float gf = sigmoidf_(g4[1]);
            const float gg = tanhf(g4[2]);
            const float go = sigmoidf_(g4[3]);
            float* cT = isL1 ? c1T : c0T;
            float* hT = (isL1 ? h1T : h0T) + (size_t)wr * HB;
            const float cp = cT[hu * BB + b];
            const float cn = fmaf(gf, cp, gi * gg);
            cT[hu * BB + b] = cn;
            hT[hu * BB + b] = go * tanhf(cn);
        }
    }
}

// ---------------- head: out[b][o] = relu(sum_k h1T[k][b]*Wout[o][k] + bout[o]) ----------
__global__ __launch_bounds__(256) void k_out(const float* __restrict__ h1T,
                                             const float* __restrict__ Wout,
                                             const float* __restrict__ bout,
                                             float* __restrict__ out) {
    const int o = blockIdx.x * 4 + (threadIdx.x >> 6);
    const int b = threadIdx.x & 63;
    float acc = 0.0f;
    const float* wrow = Wout + (size_t)o * HH;
    for (int k = 0; k < HH; k += 4) {
        const float4 wv = *reinterpret_cast<const float4*>(wrow + k);
        acc = fmaf(wv.x, h1T[(k + 0) * BB + b],
              fmaf(wv.y, h1T[(k + 1) * BB + b],
              fmaf(wv.z, h1T[(k + 2) * BB + b],
              fmaf(wv.w, h1T[(k + 3) * BB + b], acc))));
    }
    acc += bout[o];
    out[(size_t)b * 1024 + o] = fmaxf(acc, 0.0f);
}

extern "C" void kernel_launch(void* const* d_in, const int* in_sizes, int n_in,
                              void* d_out, int out_size, void* d_ws, size_t ws_size,
                              hipStream_t stream) {
    (void)in_sizes; (void)n_in; (void)out_size; (void)ws_size;
    const float* x    = (const float*)d_in[0];
    const float* Wih0 = (const float*)d_in[1];
    const float* Whh0 = (const float*)d_in[2];
    const float* bih0 = (const float*)d_in[3];
    const float* bhh0 = (const float*)d_in[4];
    const float* Wih1 = (const float*)d_in[5];
    const float* Whh1 = (const float*)d_in[6];
    const float* bih1 = (const float*)d_in[7];
    const float* bhh1 = (const float*)d_in[8];
    const float* Wout = (const float*)d_in[9];
    const float* bout = (const float*)d_in[10];

    float* ws     = (float*)d_ws;
    float* xT     = ws;                          // TT*NB = 8,192,000
    float* featsT = xT + (size_t)TT * NB;        // 8,192,000
    float* w      = featsT + (size_t)TT * NB;    // 512
    float* rowsum = w + TT;                      // 512
    float* h0T    = rowsum + TT;                 // 2*HB
    float* c0T    = h0T + 2 * (size_t)HB;        // HB
    float* h1T    = c0T + (size_t)HB;            // 2*HB
    float* c1T    = h1T + 2 * (size_t)HB;        // HB
    (void)c1T;

    // zero all LSTM state (h double-buffers + cell states are contiguous: 6*HB floats)
    hipMemsetAsync(h0T, 0, (size_t)6 * HB * sizeof(float), stream);

    k_transpose<<<dim3(TT, 63), 256, 0, stream>>>(x, xT);
    k_wrow<<<1, TT, 0, stream>>>(w, rowsum);
    k_caputo<<<dim3(TT / 4, 16), 256, 0, stream>>>(xT, w, rowsum, featsT);

    for (int s = 0; s <= TT; ++s)
        k_step<<<256, 1024, 0, stream>>>(featsT, Wih0, Whh0, bih0, bhh0,
                                         Wih1, Whh1, bih1, bhh1,
                                         h0T, c0T, h1T, c1T, s);

    k_out<<<256, 256, 0, stream>>>(h1T, Wout, bout, (float*)d_out);
}

// Round 2
// 6415.556 us; speedup vs baseline: 2.8673x; 2.8673x over previous
//
#include <hip/hip_runtime.h>
#include <cstddef>

#define BB 64      // batch
#define TT 512     // time steps
#define NN 250     // useful input features (alpha=1.0 block is zero)
#define HH 512     // hidden
#define NB (NN*BB) // 16000 floats per timestep slice
#define HB (HH*BB) // 32768 floats per hidden state
#define K0 762     // layer0 dot length: 250 feats + 512 recurrent
#define K1 1024    // layer1 dot length: 512 input + 512 recurrent

__device__ __forceinline__ float sigmoidf_(float x) { return 1.0f / (1.0f + expf(-x)); }

// ---------------- transpose x[b][t][n] -> xT[t][n][b] ----------------
__global__ __launch_bounds__(256) void k_transpose(const float* __restrict__ x,
                                                   float* __restrict__ xT) {
    const int t = blockIdx.x;
    const int n = blockIdx.y * 4 + (threadIdx.x >> 6);
    const int b = threadIdx.x & 63;
    if (n < NN)
        xT[(size_t)t * NB + n * BB + b] = x[(size_t)b * (TT * NN) + t * NN + n];
}

// ---------------- w[d] = (d+1e-6)^-0.5, rowsum[t] = sum_{d=1..t} w[d] ----------------
__global__ __launch_bounds__(512) void k_wrow(float* __restrict__ w, float* __restrict__ rowsum) {
    __shared__ float sw[TT];
    const int d = threadIdx.x;
    const float wd = (d >= 1) ? (1.0f / sqrtf((float)d + 1e-6f)) : 0.0f;
    sw[d] = wd;
    w[d] = wd;
    __syncthreads();
    float s = 0.0f;
    for (int j = 1; j <= d; ++j) s += sw[j];
    rowsum[d] = s;
}

// ---------------- caputo: featsT[t][n][b] = coef*(x*rowsum[t] - sum_{j<t} w[t-j]*x[j]) ----
__global__ __launch_bounds__(256) void k_caputo(const float* __restrict__ xT,
                                                const float* __restrict__ w,
                                                const float* __restrict__ rowsum,
                                                float* __restrict__ featsT) {
    const float COEF = 0.5641895835477563f;  // 1/gamma(0.5)
    const int t0 = blockIdx.x * 4;
    const int nb0 = blockIdx.y * 1024 + threadIdx.x;
    float acc[4][4];
#pragma unroll
    for (int a = 0; a < 4; ++a)
#pragma unroll
        for (int e = 0; e < 4; ++e) acc[a][e] = 0.0f;

    for (int j = 0; j < t0; ++j) {
        const float* xj = xT + (size_t)j * NB;
        const float wt0 = w[t0 - j];
        const float wt1 = w[t0 + 1 - j];
        const float wt2 = w[t0 + 2 - j];
        const float wt3 = w[t0 + 3 - j];
#pragma unroll
        for (int e = 0; e < 4; ++e) {
            const int nb = nb0 + e * 256;
            const float xv = (nb < NB) ? xj[nb] : 0.0f;
            acc[0][e] = fmaf(wt0, xv, acc[0][e]);
            acc[1][e] = fmaf(wt1, xv, acc[1][e]);
            acc[2][e] = fmaf(wt2, xv, acc[2][e]);
            acc[3][e] = fmaf(wt3, xv, acc[3][e]);
        }
    }
#pragma unroll
    for (int dj = 0; dj < 3; ++dj) {
        const int j = t0 + dj;
        const float* xj = xT + (size_t)j * NB;
#pragma unroll
        for (int e = 0; e < 4; ++e) {
            const int nb = nb0 + e * 256;
            const float xv = (nb < NB) ? xj[nb] : 0.0f;
#pragma unroll
            for (int tt = 0; tt < 4; ++tt)
                if (tt > dj) acc[tt][e] = fmaf(w[tt - dj], xv, acc[tt][e]);
        }
    }
#pragma unroll
    for (int tt = 0; tt < 4; ++tt) {
        const int t = t0 + tt;
        const float rs = rowsum[t];
        const float* xt = xT + (size_t)t * NB;
        float* ft = featsT + (size_t)t * NB;
#pragma unroll
        for (int e = 0; e < 4; ++e) {
            const int nb = nb0 + e * 256;
            if (nb < NB) ft[nb] = COEF * fmaf(xt[nb], rs, -acc[tt][e]);
        }
    }
}

// ---------------- weight transpose: WT[bi][k][r], r = hu_local*4 + gate ----------------
// L0: bi<128, k<762: k<250 -> Wih0[row][k], else Whh0[row][k-250]; row = g*512 + bi*4+hu_l
// L1: bi<128, k<1024: k<512 -> Wih1[row][k], else Whh1[row][k-512]
__global__ __launch_bounds__(256) void k_wt(const float* __restrict__ Wih0,
                                            const float* __restrict__ Whh0,
                                            const float* __restrict__ Wih1,
                                            const float* __restrict__ Whh1,
                                            float* __restrict__ WT0b,
                                            float* __restrict__ WT1b) {
    const int total0 = 128 * K0 * 16;
    const int total1 = 128 * K1 * 16;
    const int stride = gridDim.x * 256;
    for (int idx = blockIdx.x * 256 + threadIdx.x; idx < total0; idx += stride) {
        const int r = idx & 15;
        const int k = (idx >> 4) % K0;
        const int bi = idx / (16 * K0);
        const int row = (r & 3) * HH + bi * 4 + (r >> 2);
        WT0b[idx] = (k < NN) ? Wih0[(size_t)row * 500 + k] : Whh0[(size_t)row * HH + (k - NN)];
    }
    for (int idx = blockIdx.x * 256 + threadIdx.x; idx < total1; idx += stride) {
        const int r = idx & 15;
        const int k = (idx >> 4) % K1;
        const int bi = idx / (16 * K1);
        const int row = (r & 3) * HH + bi * 4 + (r >> 2);
        WT1b[idx] = (k < HH) ? Wih1[(size_t)row * HH + k] : Whh1[(size_t)row * HH + (k - HH)];
    }
}

// ---------------- one wavefront step ----------------
// blocks 0..127: layer0 @ t=s (owns hu = bi*4 .. bi*4+3), active when s < 512
// blocks 128..255: layer1 @ t=s-1 (hu = (bi-128)*4 ..), active when s >= 1
// wave = 64 lanes = 64 batch elems; 16 waves k-split; weights via wave-uniform (scalar) loads
__global__ __launch_bounds__(1024) void k_step2(
    const float* __restrict__ featsT,
    const float* __restrict__ WT0b, const float* __restrict__ WT1b,
    const float* __restrict__ bih0, const float* __restrict__ bhh0,
    const float* __restrict__ bih1, const float* __restrict__ bhh1,
    float* __restrict__ h0T, float* __restrict__ c0T,
    float* __restrict__ h1T, float* __restrict__ c1T, int s) {
    __shared__ float part[16][16][64];
    const int tid = threadIdx.x;
    const int b = tid & 63;
    const int wv = tid >> 6;
    const bool isL1 = (blockIdx.x >= 128);
    if (!isL1 && s >= TT) return;
    if (isL1 && s < 1) return;
    const int bi = isL1 ? (blockIdx.x - 128) : blockIdx.x;
    const int rd = (s + 1) & 1;
    const float* __restrict__ h0rd = h0T + (size_t)rd * HB;

    float acc[16];
#pragma unroll
    for (int r = 0; r < 16; ++r) acc[r] = 0.0f;

    if (!isL1) {
        const float* __restrict__ wp = WT0b + (size_t)bi * (K0 * 16);
        const int k0 = __builtin_amdgcn_readfirstlane(wv * 48);
        int k1 = k0 + 48; if (k1 > K0) k1 = K0;
        // feats segment: k in [k0, min(k1,250))
        {
            const float* __restrict__ vf = featsT + (size_t)s * NB + b;
            const int e = (k1 < NN) ? k1 : NN;
#pragma unroll 2
            for (int k = k0; k < e; ++k) {
                const float vv = vf[(size_t)k * 64];
                const float* wk = wp + k * 16;
#pragma unroll
                for (int r = 0; r < 16; ++r) acc[r] = fmaf(wk[r], vv, acc[r]);
            }
        }
        // recurrent segment: k in [max(k0,250), k1)
        {
            const float* __restrict__ vh = h0rd + b;
            const int st = (k0 > NN) ? k0 : NN;
#pragma unroll 2
            for (int k = st; k < k1; ++k) {
                const float vv = vh[(size_t)(k - NN) * 64];
                const float* wk = wp + k * 16;
#pragma unroll
                for (int r = 0; r < 16; ++r) acc[r] = fmaf(wk[r], vv, acc[r]);
            }
        }
    } else {
        const float* __restrict__ wp = WT1b + (size_t)bi * (K1 * 16);
        const int k0 = __builtin_amdgcn_readfirstlane(wv * 64);
        if (k0 < HH) {  // input segment = h0 from previous wavefront
            const float* __restrict__ vh = h0rd + b;
#pragma unroll 4
            for (int kk = 0; kk < 64; ++kk) {
                const int k = k0 + kk;
                const float vv = vh[(size_t)k * 64];
                const float* wk = wp + k * 16;
#pragma unroll
                for (int r = 0; r < 16; ++r) acc[r] = fmaf(wk[r], vv, acc[r]);
            }
        } else {        // recurrent segment = h1 prev
            const float* __restrict__ vh = h1T + (size_t)rd * HB + b;
#pragma unroll 4
            for (int kk = 0; kk < 64; ++kk) {
                const int k = k0 + kk;
                const float vv = vh[(size_t)(k - HH) * 64];
                const float* wk = wp + k * 16;
#pragma unroll
                for (int r = 0; r < 16; ++r) acc[r] = fmaf(wk[r], vv, acc[r]);
            }
        }
    }

#pragma unroll
    for (int r = 0; r < 16; ++r) part[wv][r][b] = acc[r];
    __syncthreads();

    if (wv < 4) {
        const int hu = bi * 4 + wv;
        const float* __restrict__ bi_ = isL1 ? bih1 : bih0;
        const float* __restrict__ bh_ = isL1 ? bhh1 : bhh0;
        float g4[4];
#pragma unroll
        for (int g = 0; g < 4; ++g) {
            float sum = bi_[g * HH + hu] + bh_[g * HH + hu];
#pragma unroll
            for (int i = 0; i < 16; ++i) sum += part[i][wv * 4 + g][b];
            g4[g] = sum;
        }
        const float gi = sigmoidf_(g4[0]);
        const float gf = sigmoidf_(g4[1]);
        const float gg = tanhf(g4[2]);
        const float go = sigmoidf_(g4[3]);
        float* __restrict__ cT = isL1 ? c1T : c0T;
        const float cp = cT[hu * 64 + b];
        const float cn = fmaf(gf, cp, gi * gg);
        cT[hu * 64 + b] = cn;
        float* __restrict__ hT = (isL1 ? h1T : h0T) + (size_t)(s & 1) * HB;
        hT[hu * 64 + b] = go * tanhf(cn);
    }
}

// ---------------- head: out[b][o] = relu(sum_k h1T[k][b]*Wout[o][k] + bout[o]) ----------
__global__ __launch_bounds__(256) void k_out(const float* __restrict__ h1T,
                                             const float* __restrict__ Wout,
                                             const float* __restrict__ bout,
                                             float* __restrict__ out) {
    const int o = blockIdx.x * 4 + (threadIdx.x >> 6);
    const int b = threadIdx.x & 63;
    float acc = 0.0f;
    const float* wrow = Wout + (size_t)o * HH;
    for (int k = 0; k < HH; k += 4) {
        const float4 wv = *reinterpret_cast<const float4*>(wrow + k);
        acc = fmaf(wv.x, h1T[(k + 0) * BB + b],
              fmaf(wv.y, h1T[(k + 1) * BB + b],
              fmaf(wv.z, h1T[(k + 2) * BB + b],
              fmaf(wv.w, h1T[(k + 3) * BB + b], acc))));
    }
    acc += bout[o];
    out[(size_t)b * 1024 + o] = fmaxf(acc, 0.0f);
}

extern "C" void kernel_launch(void* const* d_in, const int* in_sizes, int n_in,
                              void* d_out, int out_size, void* d_ws, size_t ws_size,
                              hipStream_t stream) {
    (void)in_sizes; (void)n_in; (void)out_size; (void)ws_size;
    const float* x    = (const float*)d_in[0];
    const float* Wih0 = (const float*)d_in[1];
    const float* Whh0 = (const float*)d_in[2];
    const float* bih0 = (const float*)d_in[3];
    const float* bhh0 = (const float*)d_in[4];
    const float* Wih1 = (const float*)d_in[5];
    const float* Whh1 = (const float*)d_in[6];
    const float* bih1 = (const float*)d_in[7];
    const float* bhh1 = (const float*)d_in[8];
    const float* Wout = (const float*)d_in[9];
    const float* bout = (const float*)d_in[10];

    float* ws     = (float*)d_ws;
    float* xT     = ws;                          // 8,192,000 floats (dead after caputo)
    float* WT0b   = ws;                          // aliases xT: 128*762*16  = 1,560,576
    float* WT1b   = WT0b + (size_t)128 * K0 * 16;//             128*1024*16 = 2,097,152
    float* featsT = xT + (size_t)TT * NB;        // 8,192,000
    float* w      = featsT + (size_t)TT * NB;    // 512
    float* rowsum = w + TT;                      // 512
    float* h0T    = rowsum + TT;                 // 2*HB
    float* c0T    = h0T + 2 * (size_t)HB;        // HB
    float* h1T    = c0T + (size_t)HB;            // 2*HB
    float* c1T    = h1T + 2 * (size_t)HB;        // HB
    (void)c1T;

    // zero all LSTM state (h double-buffers + cell states contiguous: 6*HB floats)
    hipMemsetAsync(h0T, 0, (size_t)6 * HB * sizeof(float), stream);

    k_transpose<<<dim3(TT, 63), 256, 0, stream>>>(x, xT);
    k_wrow<<<1, TT, 0, stream>>>(w, rowsum);
    k_caputo<<<dim3(TT / 4, 16), 256, 0, stream>>>(xT, w, rowsum, featsT);
    // xT dead now; build transposed weights over it
    k_wt<<<512, 256, 0, stream>>>(Wih0, Whh0, Wih1, Whh1, WT0b, WT1b);

    for (int s = 0; s <= TT; ++s)
        k_step2<<<256, 1024, 0, stream>>>(featsT, WT0b, WT1b, bih0, bhh0, bih1, bhh1,
                                          h0T, c0T, h1T, c1T, s);

    k_out<<<256, 256, 0, stream>>>(h1T, Wout, bout, (float*)d_out);
}